// Round 7
// baseline (322.946 us; speedup 1.0000x reference)
//
#include <hip/hip_runtime.h>
#include <hip/hip_bf16.h>
#include <math.h>

#define PAST 8191
#define SCALEF 0.0625f  // 256^-0.5

using bf = __hip_bfloat16;

__device__ __forceinline__ float bf2f(unsigned short u) {
    return __uint_as_float(((unsigned)u) << 16);
}
__device__ __forceinline__ void unpack8(uint4 r, float* f) {
    f[0] = __uint_as_float(r.x << 16);
    f[1] = __uint_as_float(r.x & 0xffff0000u);
    f[2] = __uint_as_float(r.y << 16);
    f[3] = __uint_as_float(r.y & 0xffff0000u);
    f[4] = __uint_as_float(r.z << 16);
    f[5] = __uint_as_float(r.z & 0xffff0000u);
    f[6] = __uint_as_float(r.w << 16);
    f[7] = __uint_as_float(r.w & 0xffff0000u);
}

// ---- dtype-generic loaders: BF16=true -> packed bf16, else fp32 ----
template<bool BF16>
__device__ __forceinline__ void load8(const void* W, size_t off, float* f) {
    if constexpr (BF16) {
        uint4 r = *reinterpret_cast<const uint4*>((const unsigned short*)W + off);
        unpack8(r, f);
    } else {
        const float* p = (const float*)W + off;
        float4 a = *reinterpret_cast<const float4*>(p);
        float4 b = *reinterpret_cast<const float4*>(p + 4);
        f[0]=a.x; f[1]=a.y; f[2]=a.z; f[3]=a.w;
        f[4]=b.x; f[5]=b.y; f[6]=b.z; f[7]=b.w;
    }
}
template<bool BF16>
__device__ __forceinline__ void load4(const void* P, size_t off, float* f) {
    if constexpr (BF16) {
        uint2 r = *reinterpret_cast<const uint2*>((const unsigned short*)P + off);
        f[0] = __uint_as_float(r.x << 16); f[1] = __uint_as_float(r.x & 0xffff0000u);
        f[2] = __uint_as_float(r.y << 16); f[3] = __uint_as_float(r.y & 0xffff0000u);
    } else {
        float4 a = *reinterpret_cast<const float4*>((const float*)P + off);
        f[0]=a.x; f[1]=a.y; f[2]=a.z; f[3]=a.w;
    }
}
template<bool BF16>
__device__ __forceinline__ float load1(const void* P, int i) {
    if constexpr (BF16) return bf2f(((const unsigned short*)P)[i]);
    else return ((const float*)P)[i];
}

// ---- dtype probe: inspect first 768 words of x (in-bounds for both dtypes) ----
__global__ __launch_bounds__(256) void probe_kernel(const unsigned int* __restrict__ xw,
                                                    int* __restrict__ flag) {
    __shared__ int cnt;
    if (threadIdx.x == 0) cnt = 0;
    __syncthreads();
    int ok = 0;
    for (int i = threadIdx.x; i < 768; i += 256) {
        unsigned e = (xw[i] >> 7) & 0xff;
        if (e >= 96 && e <= 142) ok++;
    }
    atomicAdd(&cnt, ok);
    __syncthreads();
    if (threadIdx.x == 0) *flag = (cnt > 500) ? 1 : 0;
}

// ---------------- K1: QKV partials. grid (5, 24) x 64. qkvpart[24][2560]
template<bool BF16>
__device__ void qkv_body(const void* x, const void* Wq, const void* Wk,
                         const void* Wv, float* qkvpart) {
    __shared__ float xs[64];
    int t = threadIdx.x;
    int i0 = blockIdx.y * 64;
    xs[t] = load1<BF16>(x, i0 + t);
    __syncthreads();
    int j = blockIdx.x * 512 + t * 8;
    const void* W; int stride, jl;
    if (j < 2048)      { W = Wq; stride = 2048; jl = j; }
    else if (j < 2304) { W = Wk; stride = 256;  jl = j - 2048; }
    else               { W = Wv; stride = 256;  jl = j - 2304; }
    float acc[8] = {0,0,0,0,0,0,0,0};
    #pragma unroll 4
    for (int i = 0; i < 64; ++i) {
        float f[8];
        load8<BF16>(W, (size_t)(i0 + i) * stride + jl, f);
        float xv = xs[i];
        #pragma unroll
        for (int q = 0; q < 8; ++q) acc[q] = fmaf(xv, f[q], acc[q]);
    }
    float* dst = qkvpart + (size_t)blockIdx.y * 2560 + j;
    #pragma unroll
    for (int q = 0; q < 8; ++q) dst[q] = acc[q];
}
__global__ __launch_bounds__(64) void qkv_kernel(
    const void* x, const void* Wq, const void* Wk, const void* Wv,
    float* qkvpart, const int* flag) {
    if (*flag) qkv_body<true>(x, Wq, Wk, Wv, qkvpart);
    else       qkv_body<false>(x, Wq, Wk, Wv, qkvpart);
}

// ---------------- K2: flash decode. grid 64 x 256. 128 positions/block.
template<bool BF16>
__device__ void flash_body(const float* qkvpart, const void* bq, const void* bk,
                           const void* bv, const void* k_past, const void* v_past,
                           float* opart, float* mg, float* lg) {
    __shared__ float q_s[2048];
    __shared__ float kv_new[512];
    __shared__ float s_tile[8][128];
    __shared__ float red[3 * 2048];
    int tid = threadIdx.x, w = tid >> 6, l = tid & 63;

    for (int j = tid; j < 2048; j += 256) {
        float s = 0.f;
        #pragma unroll 4
        for (int c = 0; c < 24; ++c) s += qkvpart[c * 2560 + j];
        q_s[j] = s + load1<BF16>(bq, j);
    }
    for (int j = tid; j < 512; j += 256) {
        float s = 0.f;
        #pragma unroll 4
        for (int c = 0; c < 24; ++c) s += qkvpart[c * 2560 + 2048 + j];
        s += (j < 256) ? load1<BF16>(bk, j) : load1<BF16>(bv, j - 256);
        kv_new[j] = s;
    }
    __syncthreads();

    int hi = l >> 5, d0 = (l & 31) * 8;
    float qr[8][8];
    #pragma unroll
    for (int h = 0; h < 8; ++h)
        #pragma unroll
        for (int r = 0; r < 8; ++r) qr[h][r] = q_s[h * 256 + d0 + r];

    int base = blockIdx.x * 128;
    for (int it = 0; it < 16; ++it) {
        int ploc = w * 32 + it * 2 + hi;
        int p = base + ploc;
        float kf[8];
        if (p < PAST) {
            load8<BF16>(k_past, (size_t)p * 256 + d0, kf);
        } else {
            #pragma unroll
            for (int r = 0; r < 8; ++r) kf[r] = kv_new[d0 + r];
        }
        #pragma unroll
        for (int h = 0; h < 8; ++h) {
            float s = 0.f;
            #pragma unroll
            for (int r = 0; r < 8; ++r) s = fmaf(qr[h][r], kf[r], s);
            s += __shfl_xor(s, 1, 64);
            s += __shfl_xor(s, 2, 64);
            s += __shfl_xor(s, 4, 64);
            s += __shfl_xor(s, 8, 64);
            s += __shfl_xor(s, 16, 64);
            if ((l & 31) == 0) s_tile[h][ploc] = s * SCALEF;
        }
    }
    __syncthreads();

    {
        int h = tid >> 5, ii = tid & 31;
        float v[4];
        #pragma unroll
        for (int r = 0; r < 4; ++r) v[r] = s_tile[h][ii + 32 * r];
        float m = fmaxf(fmaxf(v[0], v[1]), fmaxf(v[2], v[3]));
        m = fmaxf(m, __shfl_xor(m, 1, 64));
        m = fmaxf(m, __shfl_xor(m, 2, 64));
        m = fmaxf(m, __shfl_xor(m, 4, 64));
        m = fmaxf(m, __shfl_xor(m, 8, 64));
        m = fmaxf(m, __shfl_xor(m, 16, 64));
        float e[4], ls = 0.f;
        #pragma unroll
        for (int r = 0; r < 4; ++r) { e[r] = expf(v[r] - m); ls += e[r]; }
        ls += __shfl_xor(ls, 1, 64);
        ls += __shfl_xor(ls, 2, 64);
        ls += __shfl_xor(ls, 4, 64);
        ls += __shfl_xor(ls, 8, 64);
        ls += __shfl_xor(ls, 16, 64);
        #pragma unroll
        for (int r = 0; r < 4; ++r) s_tile[h][ii + 32 * r] = e[r];
        if (ii == 0) { mg[blockIdx.x * 8 + h] = m; lg[blockIdx.x * 8 + h] = ls; }
    }
    __syncthreads();

    int d0p = l * 4;
    float o[8][4];
    #pragma unroll
    for (int h = 0; h < 8; ++h)
        #pragma unroll
        for (int r = 0; r < 4; ++r) o[h][r] = 0.f;
    for (int it = 0; it < 32; ++it) {
        int ploc = w + it * 4;
        int p = base + ploc;
        float vf[4];
        if (p < PAST) {
            load4<BF16>(v_past, (size_t)p * 256 + d0p, vf);
        } else {
            #pragma unroll
            for (int r = 0; r < 4; ++r) vf[r] = kv_new[256 + d0p + r];
        }
        #pragma unroll
        for (int h = 0; h < 8; ++h) {
            float ph = s_tile[h][ploc];
            #pragma unroll
            for (int r = 0; r < 4; ++r) o[h][r] = fmaf(ph, vf[r], o[h][r]);
        }
    }
    if (w > 0) {
        float* dst = red + (w - 1) * 2048;
        #pragma unroll
        for (int h = 0; h < 8; ++h)
            #pragma unroll
            for (int r = 0; r < 4; ++r) dst[h * 256 + d0p + r] = o[h][r];
    }
    __syncthreads();
    if (w == 0) {
        #pragma unroll
        for (int h = 0; h < 8; ++h)
            #pragma unroll
            for (int r = 0; r < 4; ++r) {
                float v = o[h][r] + red[h*256 + d0p + r] + red[2048 + h*256 + d0p + r]
                        + red[4096 + h*256 + d0p + r];
                opart[(size_t)blockIdx.x * 2048 + h * 256 + d0p + r] = v;
            }
    }
}
__global__ __launch_bounds__(256) void flash_kernel(
    const float* qkvpart, const void* bq, const void* bk, const void* bv,
    const void* k_past, const void* v_past,
    float* opart, float* mg, float* lg, const int* flag) {
    if (*flag) flash_body<true>(qkvpart, bq, bk, bv, k_past, v_past, opart, mg, lg);
    else       flash_body<false>(qkvpart, bq, bk, bv, k_past, v_past, opart, mg, lg);
}

// ---------------- K3: o-combine + O-projection. grid (3, 32) x 64. x2part[32][1536]
template<bool BF16>
__device__ void oproj_body(const float* opart, const float* mg, const float* lg,
                           const void* Wo, float* x2part) {
    __shared__ float coef[64];
    __shared__ float xs[64];
    int t = threadIdx.x;
    int i0 = blockIdx.y * 64;
    int h = i0 >> 8;
    float mt = mg[t * 8 + h];
    float M = mt;
    M = fmaxf(M, __shfl_xor(M, 1, 64));
    M = fmaxf(M, __shfl_xor(M, 2, 64));
    M = fmaxf(M, __shfl_xor(M, 4, 64));
    M = fmaxf(M, __shfl_xor(M, 8, 64));
    M = fmaxf(M, __shfl_xor(M, 16, 64));
    M = fmaxf(M, __shfl_xor(M, 32, 64));
    float c = expf(mt - M);
    float den = lg[t * 8 + h] * c;
    den += __shfl_xor(den, 1, 64);
    den += __shfl_xor(den, 2, 64);
    den += __shfl_xor(den, 4, 64);
    den += __shfl_xor(den, 8, 64);
    den += __shfl_xor(den, 16, 64);
    den += __shfl_xor(den, 32, 64);
    coef[t] = c;
    __syncthreads();
    int i = i0 + t;
    float num = 0.f;
    #pragma unroll 4
    for (int b = 0; b < 64; ++b) num = fmaf(coef[b], opart[(size_t)b * 2048 + i], num);
    xs[t] = num / den;
    __syncthreads();
    int j = blockIdx.x * 512 + t * 8;
    float acc[8] = {0,0,0,0,0,0,0,0};
    #pragma unroll 4
    for (int k = 0; k < 64; ++k) {
        float f[8];
        load8<BF16>(Wo, (size_t)(i0 + k) * 1536 + j, f);
        float xv = xs[k];
        #pragma unroll
        for (int q = 0; q < 8; ++q) acc[q] = fmaf(xv, f[q], acc[q]);
    }
    float* dst = x2part + (size_t)blockIdx.y * 1536 + j;
    #pragma unroll
    for (int q = 0; q < 8; ++q) dst[q] = acc[q];
}
__global__ __launch_bounds__(64) void oproj_kernel(
    const float* opart, const float* mg, const float* lg, const void* Wo,
    float* x2part, const int* flag) {
    if (*flag) oproj_body<true>(opart, mg, lg, Wo, x2part);
    else       oproj_body<false>(opart, mg, lg, Wo, x2part);
}

// ---------------- K4: gate/up. grid (12, 24, 2) x 64. gupart[48][6144]
template<bool BF16>
__device__ void gateup_body(const float* x2part, const void* bo, const void* x,
                            const void* Wg, const void* Wu, float* gupart) {
    __shared__ float xs[64];
    int t = threadIdx.x;
    int i0 = blockIdx.y * 64;
    int i = i0 + t;
    float s = 0.f;
    #pragma unroll 4
    for (int c = 0; c < 32; ++c) s += x2part[c * 1536 + i];
    xs[t] = s + load1<BF16>(bo, i) + load1<BF16>(x, i);
    __syncthreads();
    const void* W = blockIdx.z ? Wu : Wg;
    int j = blockIdx.x * 512 + t * 8;
    float acc[8] = {0,0,0,0,0,0,0,0};
    #pragma unroll 4
    for (int k = 0; k < 64; ++k) {
        float f[8];
        load8<BF16>(W, (size_t)(i0 + k) * 6144 + j, f);
        float xv = xs[k];
        #pragma unroll
        for (int q = 0; q < 8; ++q) acc[q] = fmaf(xv, f[q], acc[q]);
    }
    float* dst = gupart + ((size_t)blockIdx.z * 24 + blockIdx.y) * 6144 + j;
    #pragma unroll
    for (int q = 0; q < 8; ++q) dst[q] = acc[q];
}
__global__ __launch_bounds__(64) void gateup_kernel(
    const float* x2part, const void* bo, const void* x,
    const void* Wg, const void* Wu, float* gupart, const int* flag) {
    if (*flag) gateup_body<true>(x2part, bo, x, Wg, Wu, gupart);
    else       gateup_body<false>(x2part, bo, x, Wg, Wu, gupart);
}

// ---------------- K5: GELU(g)*u @ Wd. grid (3, 96) x 64. dpart[96][1536]
template<bool BF16>
__device__ void down_body(const float* gupart, const void* bg, const void* bu,
                          const void* Wd, float* dpart) {
    __shared__ float xs[64];
    int t = threadIdx.x;
    int i0 = blockIdx.y * 64;
    int i = i0 + t;
    float g = 0.f, u = 0.f;
    #pragma unroll 4
    for (int c = 0; c < 24; ++c) {
        g += gupart[c * 6144 + i];
        u += gupart[(24 + c) * 6144 + i];
    }
    g += load1<BF16>(bg, i); u += load1<BF16>(bu, i);
    float ge = 0.5f * g * (1.0f + erff(g * 0.70710678118654752f));
    xs[t] = ge * u;
    __syncthreads();
    int j = blockIdx.x * 512 + t * 8;
    float acc[8] = {0,0,0,0,0,0,0,0};
    #pragma unroll 4
    for (int k = 0; k < 64; ++k) {
        float f[8];
        load8<BF16>(Wd, (size_t)(i0 + k) * 1536 + j, f);
        float xv = xs[k];
        #pragma unroll
        for (int q = 0; q < 8; ++q) acc[q] = fmaf(xv, f[q], acc[q]);
    }
    float* dst = dpart + (size_t)blockIdx.y * 1536 + j;
    #pragma unroll
    for (int q = 0; q < 8; ++q) dst[q] = acc[q];
}
__global__ __launch_bounds__(64) void down_kernel(
    const float* gupart, const void* bg, const void* bu, const void* Wd,
    float* dpart, const int* flag) {
    if (*flag) down_body<true>(gupart, bg, bu, Wd, dpart);
    else       down_body<false>(gupart, bg, bu, Wd, dpart);
}

// ---------------- K6: final. grid 24 x 64.
__global__ __launch_bounds__(64) void final_kernel(
    const float* __restrict__ x2part, const float* __restrict__ dpart,
    const void* __restrict__ bo, const void* __restrict__ x,
    const void* __restrict__ bd, void* __restrict__ out, const int* __restrict__ flag) {
    int j = blockIdx.x * 64 + threadIdx.x;
    int isbf = *flag;
    float x2 = 0.f;
    #pragma unroll 4
    for (int c = 0; c < 32; ++c) x2 += x2part[c * 1536 + j];
    float y = 0.f;
    #pragma unroll 4
    for (int c = 0; c < 96; ++c) y += dpart[c * 1536 + j];
    float bov, xv, bdv;
    if (isbf) {
        bov = bf2f(((const unsigned short*)bo)[j]);
        xv  = bf2f(((const unsigned short*)x)[j]);
        bdv = bf2f(((const unsigned short*)bd)[j]);
    } else {
        bov = ((const float*)bo)[j];
        xv  = ((const float*)x)[j];
        bdv = ((const float*)bd)[j];
    }
    float v = x2 + bov + xv + y + bdv;
    if (isbf) ((bf*)out)[j] = __float2bfloat16(v);
    else      ((float*)out)[j] = v;
}

extern "C" void kernel_launch(void* const* d_in, const int* in_sizes, int n_in,
                              void* d_out, int out_size, void* d_ws, size_t ws_size,
                              hipStream_t stream) {
    const void* x  = d_in[0];
    const void* kp = d_in[1];
    const void* vp = d_in[2];
    const void* Wq = d_in[3];
    const void* bq = d_in[4];
    const void* Wk = d_in[5];
    const void* bk = d_in[6];
    const void* Wv = d_in[7];
    const void* bv = d_in[8];
    const void* Wo = d_in[9];
    const void* bo = d_in[10];
    const void* Wg = d_in[11];
    const void* bg = d_in[12];
    const void* Wu = d_in[13];
    const void* bu = d_in[14];
    const void* Wd = d_in[15];
    const void* bd = d_in[16];

    float* ws = (float*)d_ws;
    float* qkvpart = ws;             // 24*2560 = 61440
    float* opart   = ws + 61440;     // 64*2048 = 131072
    float* mg      = ws + 192512;    // 512
    float* lg      = ws + 193024;    // 512
    float* x2part  = ws + 193536;    // 32*1536 = 49152
    float* gupart  = ws + 242688;    // 48*6144 = 294912
    float* dpart   = ws + 537600;    // 96*1536 = 147456
    int*  flag     = (int*)(ws + 685056);

    probe_kernel<<<1, 256, 0, stream>>>((const unsigned int*)x, flag);
    qkv_kernel<<<dim3(5, 24), 64, 0, stream>>>(x, Wq, Wk, Wv, qkvpart, flag);
    flash_kernel<<<64, 256, 0, stream>>>(qkvpart, bq, bk, bv, kp, vp, opart, mg, lg, flag);
    oproj_kernel<<<dim3(3, 32), 64, 0, stream>>>(opart, mg, lg, Wo, x2part, flag);
    gateup_kernel<<<dim3(12, 24, 2), 64, 0, stream>>>(x2part, bo, x, Wg, Wu, gupart, flag);
    down_kernel<<<dim3(3, 96), 64, 0, stream>>>(gupart, bg, bu, Wd, dpart, flag);
    final_kernel<<<24, 64, 0, stream>>>(x2part, dpart, bo, x, bd, d_out, flag);
}